// Round 10
// baseline (920.296 us; speedup 1.0000x reference)
//
#include <hip/hip_runtime.h>
#include <hip/hip_cooperative_groups.h>
#include <math.h>

namespace cg = cooperative_groups;

#define N_NODES 10000
#define N_EDGES 640000
#define DIM     128
#define NCLS    10
#define NGRAPH  64
#define NB      157    // buckets of 64 nodes (dst>>6)
#define BCAP    4608   // bucket capacity; bucket ~Poisson(4076), 8 sigma pad
#define PKCAP   2560   // coop bin-phase LDS capacity -> needs grid >= 250
#define EPBF    4000   // fallback binA edges/block (160 blocks)

typedef unsigned int uint32;
typedef unsigned short ushort16;

__device__ __forceinline__ ushort16 f32_to_bf16_rne(float f) {
    uint32 u = __float_as_uint(f);
    u = (u + 0x7fffu + ((u >> 16) & 1u)) >> 16;   // round-to-nearest-even
    return (ushort16)u;
}

// 16 rows starting at row0b: g = bf16((X@W) * (scale ? dis[row] : 1))
__device__ __forceinline__ void gemm_tile(const float* __restrict__ X,
                                          const float* __restrict__ W,
                                          const float* __restrict__ dis,
                                          int row0b, int tid, bool scale,
                                          ushort16* __restrict__ Gh) {
    int c    = tid & 127;
    int rg   = tid >> 7;
    int row0 = row0b + rg * 8;
    const float* xb = X + row0 * DIM;
    float acc[8] = {0.f, 0.f, 0.f, 0.f, 0.f, 0.f, 0.f, 0.f};
    for (int k = 0; k < DIM; k += 4) {
        float w0 = W[(k + 0) * DIM + c];
        float w1 = W[(k + 1) * DIM + c];
        float w2 = W[(k + 2) * DIM + c];
        float w3 = W[(k + 3) * DIM + c];
#pragma unroll
        for (int r = 0; r < 8; r++) {
            float4 xv = *(const float4*)(xb + r * DIM + k);
            acc[r] += xv.x * w0 + xv.y * w1 + xv.z * w2 + xv.w * w3;
        }
    }
#pragma unroll
    for (int r = 0; r < 8; r++) {
        int row = row0 + r;
        float s = scale ? dis[row] : 1.0f;
        Gh[row * DIM + c] = f32_to_bf16_rne(acc[r] * s);
    }
}

// one group = 4 nodes, one wave each; lane owns 2 bf16 feats (1 uint).
// L1: per-src dis applied during gather (g unscaled); else g pre-scaled.
template <bool L1>
__device__ __forceinline__ void agg_group(int grp, const uint32* __restrict__ g32,
                                          const int* __restrict__ deg,
                                          const ushort16* __restrict__ col,
                                          const float* __restrict__ dis,
                                          float* __restrict__ xout, int tid) {
    int v    = grp * 4 + (tid >> 6);
    int lane = tid & 63;
    const ushort16* cv = col + (v << 7);
    int dv = deg[v];
    float sv = dis[v];

    uint32 us = g32[(v << 6) + lane];
    float a0 = __uint_as_float(us << 16);
    float a1 = __uint_as_float(us & 0xffff0000u);
    if (L1) { a0 *= sv; a1 *= sv; }
    float b0 = 0.f, b1 = 0.f, c0 = 0.f, c1 = 0.f;
    float d0 = 0.f, d1 = 0.f, e0 = 0.f, e1 = 0.f;
    float f0 = 0.f, f1 = 0.f, g0 = 0.f, g1 = 0.f;
    float h0 = 0.f, h1 = 0.f, i0 = 0.f, i1 = 0.f;

    int k = 0;
    for (; k + 8 <= dv; k += 8) {
        uint4 q = *(const uint4*)(cv + k);
        int u0 = q.x & 0xffff, u1 = q.x >> 16;
        int u2 = q.y & 0xffff, u3 = q.y >> 16;
        int u4 = q.z & 0xffff, u5 = q.z >> 16;
        int u6 = q.w & 0xffff, u7 = q.w >> 16;
        uint32 w0 = g32[(u0 << 6) + lane];
        uint32 w1 = g32[(u1 << 6) + lane];
        uint32 w2 = g32[(u2 << 6) + lane];
        uint32 w3 = g32[(u3 << 6) + lane];
        uint32 w4 = g32[(u4 << 6) + lane];
        uint32 w5 = g32[(u5 << 6) + lane];
        uint32 w6 = g32[(u6 << 6) + lane];
        uint32 w7 = g32[(u7 << 6) + lane];
        float s0 = 1.f, s1 = 1.f, s2 = 1.f, s3 = 1.f;
        float s4 = 1.f, s5 = 1.f, s6 = 1.f, s7 = 1.f;
        if (L1) {
            s0 = dis[u0]; s1 = dis[u1]; s2 = dis[u2]; s3 = dis[u3];
            s4 = dis[u4]; s5 = dis[u5]; s6 = dis[u6]; s7 = dis[u7];
        }
        a0 += s0 * __uint_as_float(w0 << 16); a1 += s0 * __uint_as_float(w0 & 0xffff0000u);
        b0 += s1 * __uint_as_float(w1 << 16); b1 += s1 * __uint_as_float(w1 & 0xffff0000u);
        c0 += s2 * __uint_as_float(w2 << 16); c1 += s2 * __uint_as_float(w2 & 0xffff0000u);
        d0 += s3 * __uint_as_float(w3 << 16); d1 += s3 * __uint_as_float(w3 & 0xffff0000u);
        e0 += s4 * __uint_as_float(w4 << 16); e1 += s4 * __uint_as_float(w4 & 0xffff0000u);
        f0 += s5 * __uint_as_float(w5 << 16); f1 += s5 * __uint_as_float(w5 & 0xffff0000u);
        g0 += s6 * __uint_as_float(w6 << 16); g1 += s6 * __uint_as_float(w6 & 0xffff0000u);
        h0 += s7 * __uint_as_float(w7 << 16); h1 += s7 * __uint_as_float(w7 & 0xffff0000u);
    }
    for (; k < dv; k++) {
        int u = cv[k];
        uint32 w = g32[(u << 6) + lane];
        float s = L1 ? dis[u] : 1.f;
        i0 += s * __uint_as_float(w << 16);
        i1 += s * __uint_as_float(w & 0xffff0000u);
    }
    float r0 = sv * ((((a0 + b0) + (c0 + d0)) + ((e0 + f0) + (g0 + h0))) + i0);
    float r1 = sv * ((((a1 + b1) + (c1 + d1)) + ((e1 + f1) + (g1 + h1))) + i1);
    float2 out;
    out.x = r0 > 0.f ? r0 : 0.f;
    out.y = r1 > 0.f ? r1 : 0.f;
    *(float2*)(xout + v * DIM + lane * 2) = out;
}

__device__ __forceinline__ void pool_unit(const float* __restrict__ Xb,
                                          const int* __restrict__ batch,
                                          float* __restrict__ xr, int u, int tid) {
    if (tid >= 128) return;
    int start = u * 16;
    int b = batch[start];
    float acc = 0.f;
    for (int n = start; n < start + 16; n++) {
        int bn = batch[n];
        if (bn != b) { atomicAdd(&xr[b * DIM + tid], acc); acc = 0.f; b = bn; }
        acc += Xb[n * DIM + tid];
    }
    atomicAdd(&xr[b * DIM + tid], acc);
}

__device__ __forceinline__ void head_unit(const float* __restrict__ Xb,
                                          const float* __restrict__ fcw,
                                          const float* __restrict__ fcb,
                                          float* __restrict__ out, int u, int tid) {
    int node = u * 4 + (tid >> 6);
    int lane = tid & 63;
    if (node >= N_NODES) return;
    float xl = Xb[node * DIM + lane];
    float xh = Xb[node * DIM + 64 + lane];
    float lg[NCLS];
#pragma unroll
    for (int c = 0; c < NCLS; c++) {
        float p = xl * fcw[lane * NCLS + c] + xh * fcw[(lane + 64) * NCLS + c];
#pragma unroll
        for (int off = 32; off >= 1; off >>= 1) p += __shfl_xor(p, off, 64);
        lg[c] = p + fcb[c];
    }
    float m = lg[0];
#pragma unroll
    for (int c = 1; c < NCLS; c++) m = fmaxf(m, lg[c]);
    float s = 0.f;
#pragma unroll
    for (int c = 0; c < NCLS; c++) s += expf(lg[c] - m);
    float lse = m + logf(s);
    if (lane < NCLS) out[node * NCLS + lane] = lg[lane] - lse;
}

// ================= cooperative fused kernel =================

union SMemC {
    struct { uint32 pk[PKCAP]; int cnt[NB], off[NB], cur[NB], gpos[NB]; } a; // 12.8 KB
    struct { ushort16 adj[64 * 128]; int cnt2[64]; } b;                      // 16.6 KB
};

__global__ __launch_bounds__(256, 4) void fused_gcn(
        const int* __restrict__ src, const int* __restrict__ dst,
        const int* __restrict__ batch, const float* __restrict__ x,
        const float* __restrict__ W1, const float* __restrict__ W2,
        const float* __restrict__ W3, const float* __restrict__ W4,
        const float* __restrict__ fcw, const float* __restrict__ fcb,
        float* __restrict__ out_ls, float* __restrict__ out_xr,
        int* __restrict__ gcursor, int* __restrict__ deg,
        float* __restrict__ dis, uint32* __restrict__ bins,
        ushort16* __restrict__ col, ushort16* __restrict__ Gh,
        float* __restrict__ Xb) {
    cg::grid_group grid = cg::this_grid();
    __shared__ SMemC sm;
    int tid = threadIdx.x, bid = blockIdx.x;
    int G = (int)gridDim.x;
    const uint32* g32 = (const uint32*)Gh;

    // ---- P0: init (ws is re-poisoned 0xAA before every call) ----
    if (bid == 0) { for (int i = tid; i < NB; i += 256) gcursor[i] = 0; }
    for (int i = bid * 256 + tid; i < NGRAPH * DIM; i += G * 256) out_xr[i] = 0.f;
    grid.sync();

    // ---- P1: bin edges into per-bucket runs (coalesced global writes) ----
    {
        int epb = (N_EDGES + G - 1) / G;        // <= PKCAP for G >= 250
        int base = bid * epb;
        int cnt = N_EDGES - base;
        if (cnt > epb) cnt = epb;
        if (cnt < 0) cnt = 0;
        for (int i = tid; i < NB; i += 256) sm.a.cnt[i] = 0;
        __syncthreads();
        uint32 pr[PKCAP / 256];
#pragma unroll
        for (int it = 0; it < PKCAP / 256; it++) {
            int i = it * 256 + tid;
            uint32 p = 0xffffffffu;
            if (i < cnt) {
                int e = base + i;
                p = ((uint32)dst[e] << 16) | (uint32)src[e];
                atomicAdd(&sm.a.cnt[p >> 22], 1);   // p>>22 == dst>>6
            }
            pr[it] = p;
        }
        __syncthreads();
        if (tid < 64) {  // exclusive scan of 157 counts
            int carry = 0;
            for (int r = 0; r < 3; r++) {
                int idx = r * 64 + tid;
                int v = (idx < NB) ? sm.a.cnt[idx] : 0;
                int inc = v;
#pragma unroll
                for (int o = 1; o < 64; o <<= 1) {
                    int u = __shfl_up(inc, o, 64);
                    if (tid >= o) inc += u;
                }
                if (idx < NB) { sm.a.off[idx] = inc - v + carry; sm.a.cur[idx] = inc - v + carry; }
                carry += __shfl(inc, 63, 64);
            }
        }
        __syncthreads();
#pragma unroll
        for (int it = 0; it < PKCAP / 256; it++) {
            uint32 p = pr[it];
            if (p != 0xffffffffu) sm.a.pk[atomicAdd(&sm.a.cur[p >> 22], 1)] = p;
        }
        __syncthreads();
        if (tid < NB) sm.a.gpos[tid] = atomicAdd(&gcursor[tid], sm.a.cnt[tid]);
        __syncthreads();
        for (int i = tid; i < cnt; i += 256) {
            uint32 u = sm.a.pk[i];
            int b = u >> 22;
            int gp = sm.a.gpos[b] + (i - sm.a.off[b]);
            if (gp < BCAP) bins[b * BCAP + gp] = u;
        }
    }
    grid.sync();

    // ---- P2: binB (blocks 0..NB-1) || gemm layer 1 (blocks NB.., grid-stride) ----
    if (bid < NB) {
        if (tid < 64) sm.b.cnt2[tid] = 0;
        __syncthreads();
        int tc = gcursor[bid];
        if (tc > BCAP) tc = BCAP;
        const uint32* bb = bins + bid * BCAP;
        for (int i = tid; i < tc; i += 256) {
            uint32 u = bb[i];
            int local = (u >> 16) & 63;
            int r = atomicAdd(&sm.b.cnt2[local], 1);
            if (r < 128) sm.b.adj[(local << 7) + r] = (ushort16)(u & 0xffffu);
        }
        __syncthreads();
        uint4* dstp = (uint4*)(col + (size_t)bid * 64 * 128);
        const uint4* srcp = (const uint4*)sm.b.adj;
        for (int j = tid; j < 1024; j += 256) dstp[j] = srcp[j];
        if (tid < 64) {
            int node = bid * 64 + tid;           // arrays padded to 10240
            int c = sm.b.cnt2[tid] < 128 ? sm.b.cnt2[tid] : 128;
            deg[node] = c;
            dis[node] = rsqrtf((float)c + 1.0f);
        }
    } else {
        for (int t = bid - NB; t < 625; t += G - NB)
            gemm_tile(x, W1, dis, t * 16, tid, false, Gh);
    }
    grid.sync();

    // ---- P3: agg layer 1 (dis applied per gathered src) ----
    for (int grp = bid; grp < 2500; grp += G)
        agg_group<true>(grp, g32, deg, col, dis, Xb, tid);
    grid.sync();

    // ---- layers 2..4 ----
    const float* Ws[3] = {W2, W3, W4};
#pragma unroll
    for (int l = 0; l < 3; l++) {
        for (int t = bid; t < 625; t += G)
            gemm_tile(Xb, Ws[l], dis, t * 16, tid, true, Gh);
        grid.sync();
        for (int grp = bid; grp < 2500; grp += G)
            agg_group<false>(grp, g32, deg, col, dis, Xb, tid);
        grid.sync();
    }

    // ---- P10: pool (units 0..624) + head (units 625..3124) ----
    for (int u = bid; u < 3125; u += G) {
        if (u < 625) pool_unit(Xb, batch, out_xr, u, tid);
        else         head_unit(Xb, fcw, fcb, out_ls, u - 625, tid);
    }
}

// ================= fallback multi-kernel pipeline (R8, known good) =================

__global__ __launch_bounds__(256) void binA_gemm1(const int* __restrict__ src,
                                                  const int* __restrict__ dst,
                                                  int* __restrict__ gcursor,
                                                  uint32* __restrict__ bins,
                                                  const float* __restrict__ X,
                                                  const float* __restrict__ W,
                                                  ushort16* __restrict__ Gh) {
    __shared__ uint32 pk[EPBF];
    __shared__ int cntS[NB], offS[NB], curS[NB], gposS[NB];

    if (blockIdx.x < 625) {
        gemm_tile(X, W, (const float*)nullptr, blockIdx.x * 16, threadIdx.x, false, Gh);
        return;
    }
    int ab  = blockIdx.x - 625;
    int tid = threadIdx.x;
    for (int i = tid; i < NB; i += 256) cntS[i] = 0;
    __syncthreads();
    int base = ab * EPBF;
    uint32 pr[16];
#pragma unroll
    for (int it = 0; it < 16; it++) {
        int i = it * 256 + tid;
        uint32 p = 0xffffffffu;
        if (i < EPBF) {
            int e = base + i;
            p = ((uint32)dst[e] << 16) | (uint32)src[e];
            atomicAdd(&cntS[p >> 22], 1);
        }
        pr[it] = p;
    }
    __syncthreads();
    if (tid < 64) {
        int carry = 0;
        for (int r = 0; r < 3; r++) {
            int idx = r * 64 + tid;
            int v = (idx < NB) ? cntS[idx] : 0;
            int inc = v;
#pragma unroll
            for (int o = 1; o < 64; o <<= 1) {
                int u = __shfl_up(inc, o, 64);
                if (tid >= o) inc += u;
            }
            if (idx < NB) { offS[idx] = inc - v + carry; curS[idx] = inc - v + carry; }
            carry += __shfl(inc, 63, 64);
        }
    }
    __syncthreads();
#pragma unroll
    for (int it = 0; it < 16; it++) {
        uint32 p = pr[it];
        if (p != 0xffffffffu) pk[atomicAdd(&curS[p >> 22], 1)] = p;
    }
    __syncthreads();
    if (tid < NB) gposS[tid] = atomicAdd(&gcursor[tid], cntS[tid]);
    __syncthreads();
#pragma unroll
    for (int it = 0; it < 16; it++) {
        int i = it * 256 + tid;
        if (i < EPBF) {
            uint32 u = pk[i];
            int b = u >> 22;
            int gp = gposS[b] + (i - offS[b]);
            if (gp < BCAP) bins[b * BCAP + gp] = u;
        }
    }
}

__global__ __launch_bounds__(256) void binB(const int* __restrict__ gcursor,
                                            const uint32* __restrict__ bins,
                                            ushort16* __restrict__ col,
                                            int* __restrict__ deg,
                                            float* __restrict__ dis) {
    __shared__ ushort16 adj[64 * 128];
    __shared__ int cnt2[64];
    int b   = blockIdx.x;
    int tid = threadIdx.x;
    if (tid < 64) cnt2[tid] = 0;
    __syncthreads();
    int tc = gcursor[b];
    if (tc > BCAP) tc = BCAP;
    const uint32* bb = bins + b * BCAP;
    for (int i = tid; i < tc; i += 256) {
        uint32 u = bb[i];
        int local = (u >> 16) & 63;
        int r = atomicAdd(&cnt2[local], 1);
        if (r < 128) adj[(local << 7) + r] = (ushort16)(u & 0xffffu);
    }
    __syncthreads();
    uint4* dstp = (uint4*)(col + (size_t)b * 64 * 128);
    const uint4* srcp = (const uint4*)adj;
    for (int j = tid; j < 1024; j += 256) dstp[j] = srcp[j];
    if (tid < 64) {
        int node = b * 64 + tid;
        int c = cnt2[tid] < 128 ? cnt2[tid] : 128;
        deg[node] = c;
        dis[node] = rsqrtf((float)c + 1.0f);
    }
}

__global__ __launch_bounds__(256) void agg1_kernel(const ushort16* __restrict__ Gh,
                                                   const int* __restrict__ deg,
                                                   const ushort16* __restrict__ col,
                                                   const float* __restrict__ dis,
                                                   float* __restrict__ xout) {
    agg_group<true>(blockIdx.x, (const uint32*)Gh, deg, col, dis, xout, threadIdx.x);
}

__global__ __launch_bounds__(256) void gemm_scale(const float* __restrict__ X,
                                                  const float* __restrict__ W,
                                                  const float* __restrict__ dis,
                                                  ushort16* __restrict__ Gh) {
    gemm_tile(X, W, dis, blockIdx.x * 16, threadIdx.x, true, Gh);
}

__global__ __launch_bounds__(256) void agg_kernel(const ushort16* __restrict__ Gh,
                                                  const int* __restrict__ deg,
                                                  const ushort16* __restrict__ col,
                                                  const float* __restrict__ dis,
                                                  float* __restrict__ xout) {
    agg_group<false>(blockIdx.x, (const uint32*)Gh, deg, col, dis, xout, threadIdx.x);
}

__global__ __launch_bounds__(256) void pool_head(const float* __restrict__ x,
                                                 const int* __restrict__ batch,
                                                 const float* __restrict__ fcw,
                                                 const float* __restrict__ fcb,
                                                 float* __restrict__ xr,
                                                 float* __restrict__ out) {
    if (blockIdx.x < 625) pool_unit(x, batch, xr, blockIdx.x, threadIdx.x);
    else                  head_unit(x, fcw, fcb, out, blockIdx.x - 625, threadIdx.x);
}

// ---------------- launch ----------------

extern "C" void kernel_launch(void* const* d_in, const int* in_sizes, int n_in,
                              void* d_out, int out_size, void* d_ws, size_t ws_size,
                              hipStream_t stream) {
    const float* x     = (const float*)d_in[0];
    const int*   ei    = (const int*)d_in[1];
    const int*   srcp  = ei;
    const int*   dstp  = ei + N_EDGES;
    const int*   batch = (const int*)d_in[2];
    const float* W1    = (const float*)d_in[3];
    const float* W2    = (const float*)d_in[4];
    const float* W3    = (const float*)d_in[5];
    const float* W4    = (const float*)d_in[6];
    const float* fcw   = (const float*)d_in[7];
    const float* fcb   = (const float*)d_in[8];

    float* out_ls = (float*)d_out;                 // [N,10]
    float* out_xr = out_ls + N_NODES * NCLS;       // [64,128]

    // workspace layout (16B-aligned element offsets)
    int*      gcursor = (int*)d_ws;                           // 256
    int*      deg     = gcursor + 256;                        // 10240
    float*    dis     = (float*)(deg + 10240);                // 10240
    uint32*   bins    = (uint32*)(dis + 10240);               // NB*BCAP
    ushort16* col     = (ushort16*)(bins + NB * BCAP);        // NB*64*128
    ushort16* Gh      = col + (size_t)NB * 64 * 128;          // N*D bf16
    float*    Xb      = (float*)(Gh + (size_t)N_NODES * DIM); // N*D f32

    // ---- try the cooperative fused path (occupancy-sized, error-checked) ----
    int bpc = 0;
    hipError_t qerr = hipOccupancyMaxActiveBlocksPerMultiprocessor(&bpc, fused_gcn, 256, 0);
    int G = (qerr == hipSuccess) ? bpc * 256 : 0;   // 256 CUs
    if (G > 1024) G = 1024;
    if (G >= 320) {
        void* args[] = {
            (void*)&srcp, (void*)&dstp, (void*)&batch, (void*)&x,
            (void*)&W1, (void*)&W2, (void*)&W3, (void*)&W4,
            (void*)&fcw, (void*)&fcb, (void*)&out_ls, (void*)&out_xr,
            (void*)&gcursor, (void*)&deg, (void*)&dis, (void*)&bins,
            (void*)&col, (void*)&Gh, (void*)&Xb,
        };
        hipError_t lerr = hipLaunchCooperativeKernel((void*)fused_gcn, dim3(G),
                                                     dim3(256), args, 0, stream);
        if (lerr == hipSuccess) return;
    }

    // ---- fallback: known-good multi-kernel pipeline (R8) ----
    hipMemsetAsync(gcursor, 0, 256 * sizeof(int), stream);
    hipMemsetAsync(out_xr, 0, NGRAPH * DIM * sizeof(float), stream);

    binA_gemm1<<<785, 256, 0, stream>>>(srcp, dstp, gcursor, bins, x, W1, Gh);
    binB      <<<NB, 256, 0, stream>>>(gcursor, bins, col, deg, dis);
    agg1_kernel<<<2500, 256, 0, stream>>>(Gh, deg, col, dis, Xb);
    for (int l = 0; l < 3; l++) {
        const float* Ws[3] = {W2, W3, W4};
        gemm_scale<<<625, 256, 0, stream>>>(Xb, Ws[l], dis, Gh);
        agg_kernel<<<2500, 256, 0, stream>>>(Gh, deg, col, dis, Xb);
    }
    pool_head<<<3125, 256, 0, stream>>>(Xb, batch, fcw, fcb, out_xr, out_ls);
}

// Round 12
// 299.058 us; speedup vs baseline: 3.0773x; 3.0773x over previous
//
#include <hip/hip_runtime.h>
#include <math.h>

#define N_NODES 10000
#define N_EDGES 640000
#define DIM     128
#define NCLS    10
#define NGRAPH  64
#define NB      157    // buckets of 64 nodes (dst>>6)
#define NAB     160    // binA blocks
#define EPB     4000   // edges per binA block (160*4000 = 640000)
#define SEGC    64     // per-(block,bucket) segment capacity; Binom(4000,64/1e4) mean 25.6, P(>64)~1e-9

typedef unsigned int uint32;
typedef unsigned short ushort16;

__device__ __forceinline__ ushort16 f32_to_bf16_rne(float f) {
    uint32 u = __float_as_uint(f);
    u = (u + 0x7fffu + ((u >> 16) & 1u)) >> 16;   // round-to-nearest-even
    return (ushort16)u;
}

// 16 rows starting at row0b: g = bf16((X@W) * (scale ? dis[row] : 1))
__device__ __forceinline__ void gemm_tile(const float* __restrict__ X,
                                          const float* __restrict__ W,
                                          const float* __restrict__ dis,
                                          int row0b, int tid, bool scale,
                                          ushort16* __restrict__ Gh) {
    int c    = tid & 127;
    int rg   = tid >> 7;
    int row0 = row0b + rg * 8;
    const float* xb = X + row0 * DIM;
    float acc[8] = {0.f, 0.f, 0.f, 0.f, 0.f, 0.f, 0.f, 0.f};
    for (int k = 0; k < DIM; k += 4) {
        float w0 = W[(k + 0) * DIM + c];
        float w1 = W[(k + 1) * DIM + c];
        float w2 = W[(k + 2) * DIM + c];
        float w3 = W[(k + 3) * DIM + c];
#pragma unroll
        for (int r = 0; r < 8; r++) {
            float4 xv = *(const float4*)(xb + r * DIM + k);
            acc[r] += xv.x * w0 + xv.y * w1 + xv.z * w2 + xv.w * w3;
        }
    }
#pragma unroll
    for (int r = 0; r < 8; r++) {
        int row = row0 + r;
        float s = scale ? dis[row] : 1.0f;
        Gh[row * DIM + c] = f32_to_bf16_rne(acc[r] * s);
    }
}

// core aggregation for one node (one wave): returns the 2 features this lane owns.
// L1: per-src dis applied during gather (g unscaled); else g pre-scaled.
template <bool L1>
__device__ __forceinline__ void agg_core(int v, int lane,
                                         const uint32* __restrict__ g32,
                                         const int* __restrict__ deg,
                                         const ushort16* __restrict__ col,
                                         const float* __restrict__ dis,
                                         float& r0o, float& r1o) {
    const ushort16* cv = col + (v << 7);
    int dv = deg[v];
    float sv = dis[v];

    uint32 us = g32[(v << 6) + lane];
    float a0 = __uint_as_float(us << 16);
    float a1 = __uint_as_float(us & 0xffff0000u);
    if (L1) { a0 *= sv; a1 *= sv; }
    float b0 = 0.f, b1 = 0.f, c0 = 0.f, c1 = 0.f;
    float d0 = 0.f, d1 = 0.f, e0 = 0.f, e1 = 0.f;
    float f0 = 0.f, f1 = 0.f, g0 = 0.f, g1 = 0.f;
    float h0 = 0.f, h1 = 0.f, i0 = 0.f, i1 = 0.f;

    int k = 0;
    for (; k + 8 <= dv; k += 8) {
        uint4 q = *(const uint4*)(cv + k);
        int u0 = q.x & 0xffff, u1 = q.x >> 16;
        int u2 = q.y & 0xffff, u3 = q.y >> 16;
        int u4 = q.z & 0xffff, u5 = q.z >> 16;
        int u6 = q.w & 0xffff, u7 = q.w >> 16;
        uint32 w0 = g32[(u0 << 6) + lane];
        uint32 w1 = g32[(u1 << 6) + lane];
        uint32 w2 = g32[(u2 << 6) + lane];
        uint32 w3 = g32[(u3 << 6) + lane];
        uint32 w4 = g32[(u4 << 6) + lane];
        uint32 w5 = g32[(u5 << 6) + lane];
        uint32 w6 = g32[(u6 << 6) + lane];
        uint32 w7 = g32[(u7 << 6) + lane];
        float s0 = 1.f, s1 = 1.f, s2 = 1.f, s3 = 1.f;
        float s4 = 1.f, s5 = 1.f, s6 = 1.f, s7 = 1.f;
        if (L1) {
            s0 = dis[u0]; s1 = dis[u1]; s2 = dis[u2]; s3 = dis[u3];
            s4 = dis[u4]; s5 = dis[u5]; s6 = dis[u6]; s7 = dis[u7];
        }
        a0 += s0 * __uint_as_float(w0 << 16); a1 += s0 * __uint_as_float(w0 & 0xffff0000u);
        b0 += s1 * __uint_as_float(w1 << 16); b1 += s1 * __uint_as_float(w1 & 0xffff0000u);
        c0 += s2 * __uint_as_float(w2 << 16); c1 += s2 * __uint_as_float(w2 & 0xffff0000u);
        d0 += s3 * __uint_as_float(w3 << 16); d1 += s3 * __uint_as_float(w3 & 0xffff0000u);
        e0 += s4 * __uint_as_float(w4 << 16); e1 += s4 * __uint_as_float(w4 & 0xffff0000u);
        f0 += s5 * __uint_as_float(w5 << 16); f1 += s5 * __uint_as_float(w5 & 0xffff0000u);
        g0 += s6 * __uint_as_float(w6 << 16); g1 += s6 * __uint_as_float(w6 & 0xffff0000u);
        h0 += s7 * __uint_as_float(w7 << 16); h1 += s7 * __uint_as_float(w7 & 0xffff0000u);
    }
    for (; k < dv; k++) {
        int u = cv[k];
        uint32 w = g32[(u << 6) + lane];
        float s = L1 ? dis[u] : 1.f;
        i0 += s * __uint_as_float(w << 16);
        i1 += s * __uint_as_float(w & 0xffff0000u);
    }
    float r0 = sv * ((((a0 + b0) + (c0 + d0)) + ((e0 + f0) + (g0 + h0))) + i0);
    float r1 = sv * ((((a1 + b1) + (c1 + d1)) + ((e1 + f1) + (g1 + h1))) + i1);
    r0o = r0 > 0.f ? r0 : 0.f;
    r1o = r1 > 0.f ? r1 : 0.f;
}

// ---------------- K1: gemm1 (0..624) + atomic-free binA (625..784) + zero out_xr (785) ----------------
__global__ __launch_bounds__(256) void binA_gemm1(const int* __restrict__ src,
                                                  const int* __restrict__ dst,
                                                  const float* __restrict__ X,
                                                  const float* __restrict__ W,
                                                  int* __restrict__ cntg,
                                                  uint32* __restrict__ bins,
                                                  ushort16* __restrict__ Gh,
                                                  float* __restrict__ out_xr) {
    __shared__ uint32 pk[EPB];
    __shared__ int cntS[NB], offS[NB], curS[NB];

    if (blockIdx.x < 625) {
        gemm_tile(X, W, (const float*)nullptr, blockIdx.x * 16, threadIdx.x, false, Gh);
        return;
    }
    if (blockIdx.x == 785) {
        for (int i = threadIdx.x; i < NGRAPH * DIM; i += 256) out_xr[i] = 0.f;
        return;
    }
    int ab  = blockIdx.x - 625;     // 0..159
    int tid = threadIdx.x;
    for (int i = tid; i < NB; i += 256) cntS[i] = 0;
    __syncthreads();
    int base = ab * EPB;
    uint32 pr[16];
#pragma unroll
    for (int it = 0; it < 16; it++) {
        int i = it * 256 + tid;
        uint32 p = 0xffffffffu;               // R11 bug: this guard was missing ->
        if (i < EPB) {                        // 96 edges/block double-binned
            int e = base + i;
            p = ((uint32)dst[e] << 16) | (uint32)src[e];
            atomicAdd(&cntS[p >> 22], 1);     // p>>22 == dst>>6
        }
        pr[it] = p;
    }
    __syncthreads();
    if (tid < 64) {  // exclusive scan of 157 counts
        int carry = 0;
        for (int r = 0; r < 3; r++) {
            int idx = r * 64 + tid;
            int v = (idx < NB) ? cntS[idx] : 0;
            int inc = v;
#pragma unroll
            for (int o = 1; o < 64; o <<= 1) {
                int u = __shfl_up(inc, o, 64);
                if (tid >= o) inc += u;
            }
            if (idx < NB) { offS[idx] = inc - v + carry; curS[idx] = inc - v + carry; }
            carry += __shfl(inc, 63, 64);
        }
    }
    __syncthreads();
#pragma unroll
    for (int it = 0; it < 16; it++) {
        uint32 p = pr[it];
        if (p != 0xffffffffu)
            pk[atomicAdd(&curS[p >> 22], 1)] = p;   // relocate: LDS ordered by bucket
    }
    __syncthreads();
    // contiguous write-out to this block's private per-bucket segments
    for (int i = tid; i < EPB; i += 256) {
        uint32 u = pk[i];
        int b = u >> 22;
        int idx = i - offS[b];
        if (idx < SEGC) bins[((ab * NB + b) << 6) + idx] = u;
    }
    for (int i = tid; i < NB; i += 256) {
        int c = cntS[i];
        cntg[ab * NB + i] = c < SEGC ? c : SEGC;
    }
}

// ---------------- K2: bucket segments -> padded adjacency via LDS tile ----------------
__global__ __launch_bounds__(256) void binB(const int* __restrict__ cntg,
                                            const uint32* __restrict__ bins,
                                            ushort16* __restrict__ col,
                                            int* __restrict__ deg,
                                            float* __restrict__ dis) {
    __shared__ ushort16 adj[64 * 128];   // 16 KB
    __shared__ int cnt2[64];
    int b    = blockIdx.x;
    int tid  = threadIdx.x;
    int lane = tid & 63, wv = tid >> 6;
    if (tid < 64) cnt2[tid] = 0;
    __syncthreads();
    for (int ab = wv; ab < NAB; ab += 4) {
        int c = cntg[ab * NB + b];
        if (lane < c) {
            uint32 u = bins[((ab * NB + b) << 6) + lane];
            int local = (u >> 16) & 63;
            int r = atomicAdd(&cnt2[local], 1);
            if (r < 128) adj[(local << 7) + r] = (ushort16)(u & 0xffffu);
        }
    }
    __syncthreads();
    uint4* dstp = (uint4*)(col + (size_t)b * 64 * 128);
    const uint4* srcp = (const uint4*)adj;
    for (int j = tid; j < 1024; j += 256) dstp[j] = srcp[j];
    if (tid < 64) {
        int node = b * 64 + tid;             // arrays padded to 10240
        int c = cnt2[tid] < 128 ? cnt2[tid] : 128;
        deg[node] = c;
        dis[node] = rsqrtf((float)c + 1.0f);
    }
}

// ---------------- K3: layer-1 aggregation ----------------
__global__ __launch_bounds__(256) void agg1_kernel(const ushort16* __restrict__ Gh,
                                                   const int* __restrict__ deg,
                                                   const ushort16* __restrict__ col,
                                                   const float* __restrict__ dis,
                                                   float* __restrict__ xout) {
    int v = blockIdx.x * 4 + (threadIdx.x >> 6);
    int lane = threadIdx.x & 63;
    float r0, r1;
    agg_core<true>(v, lane, (const uint32*)Gh, deg, col, dis, r0, r1);
    float2 o; o.x = r0; o.y = r1;
    *(float2*)(xout + v * DIM + lane * 2) = o;
}

// ---------------- K4/K6/K8: gemm layers 2-4 ----------------
__global__ __launch_bounds__(256) void gemm_scale(const float* __restrict__ X,
                                                  const float* __restrict__ W,
                                                  const float* __restrict__ dis,
                                                  ushort16* __restrict__ Gh) {
    gemm_tile(X, W, dis, blockIdx.x * 16, threadIdx.x, true, Gh);
}

// ---------------- K5/K7: agg layers 2-3 ----------------
__global__ __launch_bounds__(256) void agg_kernel(const ushort16* __restrict__ Gh,
                                                  const int* __restrict__ deg,
                                                  const ushort16* __restrict__ col,
                                                  const float* __restrict__ dis,
                                                  float* __restrict__ xout) {
    int v = blockIdx.x * 4 + (threadIdx.x >> 6);
    int lane = threadIdx.x & 63;
    float r0, r1;
    agg_core<false>(v, lane, (const uint32*)Gh, deg, col, dis, r0, r1);
    float2 o; o.x = r0; o.y = r1;
    *(float2*)(xout + v * DIM + lane * 2) = o;
}

// ---------------- K9: agg layer 4 + fused head (log_softmax) + pool (atomic) ----------------
__global__ __launch_bounds__(256) void agg4_head_pool(const ushort16* __restrict__ Gh,
                                                      const int* __restrict__ deg,
                                                      const ushort16* __restrict__ col,
                                                      const float* __restrict__ dis,
                                                      const int* __restrict__ batch,
                                                      const float* __restrict__ fcw,
                                                      const float* __restrict__ fcb,
                                                      float* __restrict__ out_ls,
                                                      float* __restrict__ out_xr) {
    int v = blockIdx.x * 4 + (threadIdx.x >> 6);
    int lane = threadIdx.x & 63;
    float r0, r1;
    agg_core<false>(v, lane, (const uint32*)Gh, deg, col, dis, r0, r1);

    // head: lane owns features 2*lane (r0) and 2*lane+1 (r1)
    const float* fw = fcw + (2 * lane) * NCLS;
    float lg[NCLS];
#pragma unroll
    for (int c = 0; c < NCLS; c++) {
        float p = r0 * fw[c] + r1 * fw[NCLS + c];
#pragma unroll
        for (int off = 32; off >= 1; off >>= 1) p += __shfl_xor(p, off, 64);
        lg[c] = p + fcb[c];
    }
    float m = lg[0];
#pragma unroll
    for (int c = 1; c < NCLS; c++) m = fmaxf(m, lg[c]);
    float s = 0.f;
#pragma unroll
    for (int c = 0; c < NCLS; c++) s += expf(lg[c] - m);
    float lse = m + logf(s);
    if (lane < NCLS) out_ls[v * NCLS + lane] = lg[lane] - lse;

    // pool: batch[v] is wave-uniform
    int g = batch[v];
    atomicAdd(&out_xr[g * DIM + 2 * lane], r0);
    atomicAdd(&out_xr[g * DIM + 2 * lane + 1], r1);
}

// ---------------- launch: 9 dispatches, no memsets ----------------

extern "C" void kernel_launch(void* const* d_in, const int* in_sizes, int n_in,
                              void* d_out, int out_size, void* d_ws, size_t ws_size,
                              hipStream_t stream) {
    const float* x     = (const float*)d_in[0];
    const int*   ei    = (const int*)d_in[1];      // [2, E] int32
    const int*   srcp  = ei;
    const int*   dstp  = ei + N_EDGES;
    const int*   batch = (const int*)d_in[2];
    const float* W2    = (const float*)d_in[4];
    const float* W3    = (const float*)d_in[5];
    const float* W4    = (const float*)d_in[6];
    const float* fcw   = (const float*)d_in[7];
    const float* fcb   = (const float*)d_in[8];

    float* out_ls = (float*)d_out;                 // [N,10]
    float* out_xr = out_ls + N_NODES * NCLS;       // [64,128]

    // workspace layout (16B-aligned element offsets)
    int*      cntg = (int*)d_ws;                           // NAB*NB ints (pad 25600)
    int*      deg  = cntg + 25600;                         // 10240
    float*    dis  = (float*)(deg + 10240);                // 10240
    uint32*   bins = (uint32*)(dis + 10240);               // NAB*NB*SEGC (6.43MB)
    ushort16* col  = (ushort16*)(bins + (size_t)NAB * NB * SEGC); // NB*64*128 (2.57MB)
    ushort16* Gh   = col + (size_t)NB * 64 * 128;          // N*D bf16
    float*    Xb   = (float*)(Gh + (size_t)N_NODES * DIM); // N*D f32

    binA_gemm1<<<786, 256, 0, stream>>>(srcp, dstp, x, (const float*)d_in[3],
                                        cntg, bins, Gh, out_xr);
    binB      <<<NB, 256, 0, stream>>>(cntg, bins, col, deg, dis);
    agg1_kernel<<<2500, 256, 0, stream>>>(Gh, deg, col, dis, Xb);

    gemm_scale<<<625, 256, 0, stream>>>(Xb, W2, dis, Gh);
    agg_kernel<<<2500, 256, 0, stream>>>(Gh, deg, col, dis, Xb);
    gemm_scale<<<625, 256, 0, stream>>>(Xb, W3, dis, Gh);
    agg_kernel<<<2500, 256, 0, stream>>>(Gh, deg, col, dis, Xb);
    gemm_scale<<<625, 256, 0, stream>>>(Xb, W4, dis, Gh);
    agg4_head_pool<<<2500, 256, 0, stream>>>(Gh, deg, col, dis, batch,
                                             fcw, fcb, out_ls, out_xr);
}

// Round 13
// 283.674 us; speedup vs baseline: 3.2442x; 1.0542x over previous
//
#include <hip/hip_runtime.h>
#include <math.h>

#define N_NODES 10000
#define N_EDGES 640000
#define DIM     128
#define NCLS    10
#define NGRAPH  64
#define NB      157    // buckets of 64 nodes (dst>>6)
#define BCAP    4608   // dense bucket capacity; bucket ~4076 avg, 8 sigma pad
#define EPB     4000   // edges per binA block (160 blocks)

typedef unsigned int uint32;
typedef unsigned short ushort16;

__device__ __forceinline__ ushort16 f32_to_bf16_rne(float f) {
    uint32 u = __float_as_uint(f);
    u = (u + 0x7fffu + ((u >> 16) & 1u)) >> 16;   // round-to-nearest-even
    return (ushort16)u;
}

// 16 rows starting at row0b: g = bf16((X@W) * (scale ? dis[row] : 1))
__device__ __forceinline__ void gemm_tile(const float* __restrict__ X,
                                          const float* __restrict__ W,
                                          const float* __restrict__ dis,
                                          int row0b, int tid, bool scale,
                                          ushort16* __restrict__ Gh) {
    int c    = tid & 127;
    int rg   = tid >> 7;
    int row0 = row0b + rg * 8;
    const float* xb = X + row0 * DIM;
    float acc[8] = {0.f, 0.f, 0.f, 0.f, 0.f, 0.f, 0.f, 0.f};
    for (int k = 0; k < DIM; k += 4) {
        float w0 = W[(k + 0) * DIM + c];
        float w1 = W[(k + 1) * DIM + c];
        float w2 = W[(k + 2) * DIM + c];
        float w3 = W[(k + 3) * DIM + c];
#pragma unroll
        for (int r = 0; r < 8; r++) {
            float4 xv = *(const float4*)(xb + r * DIM + k);
            acc[r] += xv.x * w0 + xv.y * w1 + xv.z * w2 + xv.w * w3;
        }
    }
#pragma unroll
    for (int r = 0; r < 8; r++) {
        int row = row0 + r;
        float s = scale ? dis[row] : 1.0f;
        Gh[row * DIM + c] = f32_to_bf16_rne(acc[r] * s);
    }
}

// core aggregation for one node (one wave): returns the 2 features this lane owns.
template <bool L1>
__device__ __forceinline__ void agg_core(int v, int lane,
                                         const uint32* __restrict__ g32,
                                         const int* __restrict__ deg,
                                         const ushort16* __restrict__ col,
                                         const float* __restrict__ dis,
                                         float& r0o, float& r1o) {
    const ushort16* cv = col + (v << 7);
    int dv = deg[v];
    float sv = dis[v];

    uint32 us = g32[(v << 6) + lane];
    float a0 = __uint_as_float(us << 16);
    float a1 = __uint_as_float(us & 0xffff0000u);
    if (L1) { a0 *= sv; a1 *= sv; }
    float b0 = 0.f, b1 = 0.f, c0 = 0.f, c1 = 0.f;
    float d0 = 0.f, d1 = 0.f, e0 = 0.f, e1 = 0.f;
    float f0 = 0.f, f1 = 0.f, g0 = 0.f, g1 = 0.f;
    float h0 = 0.f, h1 = 0.f, i0 = 0.f, i1 = 0.f;

    int k = 0;
    for (; k + 8 <= dv; k += 8) {
        uint4 q = *(const uint4*)(cv + k);
        int u0 = q.x & 0xffff, u1 = q.x >> 16;
        int u2 = q.y & 0xffff, u3 = q.y >> 16;
        int u4 = q.z & 0xffff, u5 = q.z >> 16;
        int u6 = q.w & 0xffff, u7 = q.w >> 16;
        uint32 w0 = g32[(u0 << 6) + lane];
        uint32 w1 = g32[(u1 << 6) + lane];
        uint32 w2 = g32[(u2 << 6) + lane];
        uint32 w3 = g32[(u3 << 6) + lane];
        uint32 w4 = g32[(u4 << 6) + lane];
        uint32 w5 = g32[(u5 << 6) + lane];
        uint32 w6 = g32[(u6 << 6) + lane];
        uint32 w7 = g32[(u7 << 6) + lane];
        float s0 = 1.f, s1 = 1.f, s2 = 1.f, s3 = 1.f;
        float s4 = 1.f, s5 = 1.f, s6 = 1.f, s7 = 1.f;
        if (L1) {
            s0 = dis[u0]; s1 = dis[u1]; s2 = dis[u2]; s3 = dis[u3];
            s4 = dis[u4]; s5 = dis[u5]; s6 = dis[u6]; s7 = dis[u7];
        }
        a0 += s0 * __uint_as_float(w0 << 16); a1 += s0 * __uint_as_float(w0 & 0xffff0000u);
        b0 += s1 * __uint_as_float(w1 << 16); b1 += s1 * __uint_as_float(w1 & 0xffff0000u);
        c0 += s2 * __uint_as_float(w2 << 16); c1 += s2 * __uint_as_float(w2 & 0xffff0000u);
        d0 += s3 * __uint_as_float(w3 << 16); d1 += s3 * __uint_as_float(w3 & 0xffff0000u);
        e0 += s4 * __uint_as_float(w4 << 16); e1 += s4 * __uint_as_float(w4 & 0xffff0000u);
        f0 += s5 * __uint_as_float(w5 << 16); f1 += s5 * __uint_as_float(w5 & 0xffff0000u);
        g0 += s6 * __uint_as_float(w6 << 16); g1 += s6 * __uint_as_float(w6 & 0xffff0000u);
        h0 += s7 * __uint_as_float(w7 << 16); h1 += s7 * __uint_as_float(w7 & 0xffff0000u);
    }
    for (; k < dv; k++) {
        int u = cv[k];
        uint32 w = g32[(u << 6) + lane];
        float s = L1 ? dis[u] : 1.f;
        i0 += s * __uint_as_float(w << 16);
        i1 += s * __uint_as_float(w & 0xffff0000u);
    }
    float r0 = sv * ((((a0 + b0) + (c0 + d0)) + ((e0 + f0) + (g0 + h0))) + i0);
    float r1 = sv * ((((a1 + b1) + (c1 + d1)) + ((e1 + f1) + (g1 + h1))) + i1);
    r0o = r0 > 0.f ? r0 : 0.f;
    r1o = r1 > 0.f ? r1 : 0.f;
}

// ---------------- K1: gemm1 (0..624) + R8 binA (625..784) + zero out_xr (785) ----------------
// binA: global-cursor dense buckets — the measured-best (R8, 277us) build path.
__global__ __launch_bounds__(256) void binA_gemm1(const int* __restrict__ src,
                                                  const int* __restrict__ dst,
                                                  const float* __restrict__ X,
                                                  const float* __restrict__ W,
                                                  int* __restrict__ gcursor,
                                                  uint32* __restrict__ bins,
                                                  ushort16* __restrict__ Gh,
                                                  float* __restrict__ out_xr) {
    __shared__ uint32 pk[EPB];
    __shared__ int cntS[NB], offS[NB], curS[NB], gposS[NB];

    if (blockIdx.x < 625) {
        gemm_tile(X, W, (const float*)nullptr, blockIdx.x * 16, threadIdx.x, false, Gh);
        return;
    }
    if (blockIdx.x == 785) {
        for (int i = threadIdx.x; i < NGRAPH * DIM; i += 256) out_xr[i] = 0.f;
        return;
    }
    int ab  = blockIdx.x - 625;     // 0..159
    int tid = threadIdx.x;
    for (int i = tid; i < NB; i += 256) cntS[i] = 0;
    __syncthreads();
    int base = ab * EPB;
    uint32 pr[16];
#pragma unroll
    for (int it = 0; it < 16; it++) {
        int i = it * 256 + tid;
        uint32 p = 0xffffffffu;
        if (i < EPB) {                        // bounds guard (R11 lesson)
            int e = base + i;
            p = ((uint32)dst[e] << 16) | (uint32)src[e];
            atomicAdd(&cntS[p >> 22], 1);     // p>>22 == dst>>6
        }
        pr[it] = p;
    }
    __syncthreads();
    if (tid < 64) {  // exclusive scan of 157 counts
        int carry = 0;
        for (int r = 0; r < 3; r++) {
            int idx = r * 64 + tid;
            int v = (idx < NB) ? cntS[idx] : 0;
            int inc = v;
#pragma unroll
            for (int o = 1; o < 64; o <<= 1) {
                int u = __shfl_up(inc, o, 64);
                if (tid >= o) inc += u;
            }
            if (idx < NB) { offS[idx] = inc - v + carry; curS[idx] = inc - v + carry; }
            carry += __shfl(inc, 63, 64);
        }
    }
    __syncthreads();
#pragma unroll
    for (int it = 0; it < 16; it++) {
        uint32 p = pr[it];
        if (p != 0xffffffffu)
            pk[atomicAdd(&curS[p >> 22], 1)] = p;   // relocate: LDS ordered by bucket
    }
    __syncthreads();
    if (tid < NB) gposS[tid] = atomicAdd(&gcursor[tid], cntS[tid]);
    __syncthreads();
#pragma unroll
    for (int it = 0; it < 16; it++) {
        int i = it * 256 + tid;
        if (i < EPB) {
            uint32 u = pk[i];
            int b = u >> 22;
            int gp = gposS[b] + (i - offS[b]);
            if (gp < BCAP) bins[b * BCAP + gp] = u;
        }
    }
}

// ---------------- K2: dense bucket run -> padded adjacency via LDS tile (R8) ----------------
__global__ __launch_bounds__(256) void binB(const int* __restrict__ gcursor,
                                            const uint32* __restrict__ bins,
                                            ushort16* __restrict__ col,
                                            int* __restrict__ deg,
                                            float* __restrict__ dis) {
    __shared__ ushort16 adj[64 * 128];   // 16 KB
    __shared__ int cnt2[64];
    int b   = blockIdx.x;
    int tid = threadIdx.x;
    if (tid < 64) cnt2[tid] = 0;
    __syncthreads();
    int tc = gcursor[b];
    if (tc > BCAP) tc = BCAP;
    const uint32* bb = bins + b * BCAP;
    for (int i = tid; i < tc; i += 256) {
        uint32 u = bb[i];
        int local = (u >> 16) & 63;
        int r = atomicAdd(&cnt2[local], 1);
        if (r < 128) adj[(local << 7) + r] = (ushort16)(u & 0xffffu);
    }
    __syncthreads();
    uint4* dstp = (uint4*)(col + (size_t)b * 64 * 128);
    const uint4* srcp = (const uint4*)adj;
    for (int j = tid; j < 1024; j += 256) dstp[j] = srcp[j];
    if (tid < 64) {
        int node = b * 64 + tid;             // arrays padded to 10240
        int c = cnt2[tid] < 128 ? cnt2[tid] : 128;
        deg[node] = c;
        dis[node] = rsqrtf((float)c + 1.0f);
    }
}

// ---------------- K3: layer-1 aggregation ----------------
__global__ __launch_bounds__(256) void agg1_kernel(const ushort16* __restrict__ Gh,
                                                   const int* __restrict__ deg,
                                                   const ushort16* __restrict__ col,
                                                   const float* __restrict__ dis,
                                                   float* __restrict__ xout) {
    int v = blockIdx.x * 4 + (threadIdx.x >> 6);
    int lane = threadIdx.x & 63;
    float r0, r1;
    agg_core<true>(v, lane, (const uint32*)Gh, deg, col, dis, r0, r1);
    float2 o; o.x = r0; o.y = r1;
    *(float2*)(xout + v * DIM + lane * 2) = o;
}

// ---------------- K4/K6/K8: gemm layers 2-4 ----------------
__global__ __launch_bounds__(256) void gemm_scale(const float* __restrict__ X,
                                                  const float* __restrict__ W,
                                                  const float* __restrict__ dis,
                                                  ushort16* __restrict__ Gh) {
    gemm_tile(X, W, dis, blockIdx.x * 16, threadIdx.x, true, Gh);
}

// ---------------- K5/K7: agg layers 2-3 ----------------
__global__ __launch_bounds__(256) void agg_kernel(const ushort16* __restrict__ Gh,
                                                  const int* __restrict__ deg,
                                                  const ushort16* __restrict__ col,
                                                  const float* __restrict__ dis,
                                                  float* __restrict__ xout) {
    int v = blockIdx.x * 4 + (threadIdx.x >> 6);
    int lane = threadIdx.x & 63;
    float r0, r1;
    agg_core<false>(v, lane, (const uint32*)Gh, deg, col, dis, r0, r1);
    float2 o; o.x = r0; o.y = r1;
    *(float2*)(xout + v * DIM + lane * 2) = o;
}

// ---------------- K9: agg layer 4 + fused head (log_softmax) + pool (atomic) ----------------
__global__ __launch_bounds__(256) void agg4_head_pool(const ushort16* __restrict__ Gh,
                                                      const int* __restrict__ deg,
                                                      const ushort16* __restrict__ col,
                                                      const float* __restrict__ dis,
                                                      const int* __restrict__ batch,
                                                      const float* __restrict__ fcw,
                                                      const float* __restrict__ fcb,
                                                      float* __restrict__ out_ls,
                                                      float* __restrict__ out_xr) {
    int v = blockIdx.x * 4 + (threadIdx.x >> 6);
    int lane = threadIdx.x & 63;
    float r0, r1;
    agg_core<false>(v, lane, (const uint32*)Gh, deg, col, dis, r0, r1);

    // head: lane owns features 2*lane (r0) and 2*lane+1 (r1)
    const float* fw = fcw + (2 * lane) * NCLS;
    float lg[NCLS];
#pragma unroll
    for (int c = 0; c < NCLS; c++) {
        float p = r0 * fw[c] + r1 * fw[NCLS + c];
#pragma unroll
        for (int off = 32; off >= 1; off >>= 1) p += __shfl_xor(p, off, 64);
        lg[c] = p + fcb[c];
    }
    float m = lg[0];
#pragma unroll
    for (int c = 1; c < NCLS; c++) m = fmaxf(m, lg[c]);
    float s = 0.f;
#pragma unroll
    for (int c = 0; c < NCLS; c++) s += expf(lg[c] - m);
    float lse = m + logf(s);
    if (lane < NCLS) out_ls[v * NCLS + lane] = lg[lane] - lse;

    // pool: batch[v] is wave-uniform; ~156 adds/address over 8192 addresses
    int g = batch[v];
    atomicAdd(&out_xr[g * DIM + 2 * lane], r0);
    atomicAdd(&out_xr[g * DIM + 2 * lane + 1], r1);
}

// ---------------- launch: 1 tiny memset + 9 kernels ----------------

extern "C" void kernel_launch(void* const* d_in, const int* in_sizes, int n_in,
                              void* d_out, int out_size, void* d_ws, size_t ws_size,
                              hipStream_t stream) {
    const float* x     = (const float*)d_in[0];
    const int*   ei    = (const int*)d_in[1];      // [2, E] int32
    const int*   srcp  = ei;
    const int*   dstp  = ei + N_EDGES;
    const int*   batch = (const int*)d_in[2];
    const float* W2    = (const float*)d_in[4];
    const float* W3    = (const float*)d_in[5];
    const float* W4    = (const float*)d_in[6];
    const float* fcw   = (const float*)d_in[7];
    const float* fcb   = (const float*)d_in[8];

    float* out_ls = (float*)d_out;                 // [N,10]
    float* out_xr = out_ls + N_NODES * NCLS;       // [64,128]

    // workspace layout (16B-aligned element offsets)
    int*      gcursor = (int*)d_ws;                           // 256 ints
    int*      deg     = gcursor + 256;                        // 10240
    float*    dis     = (float*)(deg + 10240);                // 10240
    uint32*   bins    = (uint32*)(dis + 10240);               // NB*BCAP (2.89MB)
    ushort16* col     = (ushort16*)(bins + NB * BCAP);        // NB*64*128 (2.57MB)
    ushort16* Gh      = col + (size_t)NB * 64 * 128;          // N*D bf16
    float*    Xb      = (float*)(Gh + (size_t)N_NODES * DIM); // N*D f32

    hipMemsetAsync(gcursor, 0, 256 * sizeof(int), stream);    // 1KB — cheap

    binA_gemm1<<<786, 256, 0, stream>>>(srcp, dstp, x, (const float*)d_in[3],
                                        gcursor, bins, Gh, out_xr);
    binB      <<<NB, 256, 0, stream>>>(gcursor, bins, col, deg, dis);
    agg1_kernel<<<2500, 256, 0, stream>>>(Gh, deg, col, dis, Xb);

    gemm_scale<<<625, 256, 0, stream>>>(Xb, W2, dis, Gh);
    agg_kernel<<<2500, 256, 0, stream>>>(Gh, deg, col, dis, Xb);
    gemm_scale<<<625, 256, 0, stream>>>(Xb, W3, dis, Gh);
    agg_kernel<<<2500, 256, 0, stream>>>(Gh, deg, col, dis, Xb);
    gemm_scale<<<625, 256, 0, stream>>>(Xb, W4, dis, Gh);
    agg4_head_pool<<<2500, 256, 0, stream>>>(Gh, deg, col, dis, batch,
                                             fcw, fcb, out_ls, out_xr);
}